// Round 5
// baseline (2401.194 us; speedup 1.0000x reference)
//
#include <hip/hip_runtime.h>
#include <hip/hip_bf16.h>
#include <hip/hip_fp16.h>

#define T_STEPS 512
#define BATCH   64
#define DIM     512            // INPUT_DIM == RNN_DIM
#define REG_KT  12             // k-tiles of Wh pinned in registers (192 regs — proven in R2/R3)
#define STR_KT  4              // k-tiles streamed from L2 each step (VMEM pipe)

typedef _Float16 half2_t __attribute__((ext_vector_type(2)));
typedef _Float16 half4_t __attribute__((ext_vector_type(4)));
typedef _Float16 half8_t __attribute__((ext_vector_type(8)));
typedef short    bf16x8 __attribute__((ext_vector_type(8)));
typedef float    f32x4  __attribute__((ext_vector_type(4)));

static __device__ __forceinline__ unsigned short f2bf(float f) {
    union { float f; unsigned u; } v; v.f = f;
    unsigned r = v.u + 0x7fffu + ((v.u >> 16) & 1u);   // RNE
    return (unsigned short)(r >> 16);
}

static __device__ __forceinline__ float fast_tanh(float x) {
    float e = __expf(2.0f * x);
    return 1.0f - 2.0f * __builtin_amdgcn_rcpf(e + 1.0f);
}

// ------------- K1: transpose 512x512 fp32 region -> bf16 (for Wx^T, gemm B-operand) -------------
__global__ __launch_bounds__(256) void tr_cvt_kernel(const float* __restrict__ src,
                                                     unsigned short* __restrict__ dst) {
    __shared__ float tile[32][33];
    const int bx = blockIdx.x * 32;
    const int by = blockIdx.y * 32;
    const int tx = threadIdx.x;       // 32
    const int ty = threadIdx.y;       // 8
    #pragma unroll
    for (int i = ty; i < 32; i += 8)
        tile[i][tx] = src[(size_t)(by + i) * DIM + (bx + tx)];
    __syncthreads();
    #pragma unroll
    for (int i = ty; i < 32; i += 8)
        dst[(size_t)(bx + i) * DIM + (by + tx)] = f2bf(tile[tx][i]);
}

// ------------- K1c: transpose Wh (rows 512..1023 of W) -> f16 WhT[col][k] -------------
__global__ __launch_bounds__(256) void tr_cvt_f16_kernel(const float* __restrict__ src,  // W + 512*512
                                                         _Float16* __restrict__ dst) {  // [512 col][512 k]
    __shared__ float tile[32][33];
    const int bx = blockIdx.x * 32;
    const int by = blockIdx.y * 32;
    const int tx = threadIdx.x;
    const int ty = threadIdx.y;
    #pragma unroll
    for (int i = ty; i < 32; i += 8)
        tile[i][tx] = src[(size_t)(by + i) * DIM + (bx + tx)];
    __syncthreads();
    #pragma unroll
    for (int i = ty; i < 32; i += 8)
        dst[(size_t)(bx + i) * DIM + (by + tx)] = (_Float16)tile[tx][i];
}

// ---------------- K2: Z = X @ Wx + bias  (bf16 MFMA), output in K3 per-thread frag order --------
// K3 thread (w, l=q*16+l15) in WG b owns Z[brow=b*16+l15][col=w*64+ct*16+q*4+rg] at i=ct*4+rg.
// Zws[t][(b*8+w)*64 + l][i]
__global__ __launch_bounds__(256) void gemm_z_kernel(const float* __restrict__ X,            // [32768][512] f32
                                                     const unsigned short* __restrict__ WxT, // [512 n][512 k] bf16
                                                     const float* __restrict__ bias,         // [512]
                                                     _Float16* __restrict__ Zo) {            // [512][4][8][64][16] f16
    const int bm   = blockIdx.y;
    const int bn   = blockIdx.x;
    const int wave = threadIdx.x >> 6;
    const int lane = threadIdx.x & 63;
    const int mBase = bm * 128 + (wave >> 1) * 64;
    const int nBase = bn * 128 + (wave & 1) * 64;
    const int l15 = lane & 15;
    const int q   = lane >> 4;
    f32x4 acc[4][4] = {};
    for (int kt = 0; kt < 512; kt += 32) {
        const int kk = kt + q * 8;
        bf16x8 a[4], b[4];
        #pragma unroll
        for (int i = 0; i < 4; ++i) {
            const float* ap = X + (size_t)(mBase + i * 16 + l15) * DIM + kk;
            float4 f0 = *(const float4*)(ap);
            float4 f1 = *(const float4*)(ap + 4);
            bf16x8 av;
            av[0] = (short)f2bf(f0.x); av[1] = (short)f2bf(f0.y);
            av[2] = (short)f2bf(f0.z); av[3] = (short)f2bf(f0.w);
            av[4] = (short)f2bf(f1.x); av[5] = (short)f2bf(f1.y);
            av[6] = (short)f2bf(f1.z); av[7] = (short)f2bf(f1.w);
            a[i] = av;
        }
        #pragma unroll
        for (int i = 0; i < 4; ++i)
            b[i] = *(const bf16x8*)(WxT + (size_t)(nBase + i * 16 + l15) * DIM + kk);
        #pragma unroll
        for (int mi = 0; mi < 4; ++mi)
            #pragma unroll
            for (int ni = 0; ni < 4; ++ni)
                acc[mi][ni] = __builtin_amdgcn_mfma_f32_16x16x32_bf16(a[mi], b[ni], acc[mi][ni], 0, 0, 0);
    }
    #pragma unroll
    for (int ni = 0; ni < 4; ++ni) {
        const int col = nBase + ni * 16 + l15;
        const float bv = bias[col];
        const int w_  = col >> 6;
        const int c64 = col & 63;
        const int ct_ = c64 >> 4;
        const int q_  = (c64 & 15) >> 2;
        const int rg_ = c64 & 3;
        #pragma unroll
        for (int mi = 0; mi < 4; ++mi) {
            #pragma unroll
            for (int rg = 0; rg < 4; ++rg) {
                const int row = mBase + mi * 16 + q * 4 + rg;
                const int t_ = row >> 6, batch = row & 63;
                const int b_ = batch >> 4, l15k = batch & 15;
                Zo[(size_t)t_ * 32768 + (size_t)((b_ * 8 + w_) * 64 + (q_ * 16 + l15k)) * 16 + ct_ * 4 + rg_] =
                    (_Float16)(acc[mi][ni][rg] + bv);
            }
        }
    }
}

// ---------------- K3: C^T MFMA recurrence, 4 WGs x 512 thr; 16 batch rows per WG ----------------
// mfma_f32_16x16x32_f16(A=W-frag, B=h-frag):
//   A: lane L holds WhT[col'=ct*16+(L&15)+wbase][k=kt*32+(L>>4)*8+e]
//   B: lane L holds h[brow=L&15][same k]           (identical layout to R3's Ah buffer)
//   C: thread holds (brow=L&15, cols = (L>>4)*4+rg + ct*16 + wbase)
// => a thread's 4 rg values are 4 CONSECUTIVE k-elems of one h-frag slot: ONE ds_write_b64 per ct
//    (4 writes/thread/step vs 16 b16), and out-stores become 4x global_store_dwordx4.
// W: 12 k-tiles pinned in regs (192 — the R2/R3-proven footprint; AGPR-native as MFMA operand),
//    4 k-tiles streamed from L2 per step (128 KB/CU/step on the VMEM pipe, WhT is L2-resident).
// LDS: only h, double-buffered 2x16 KB, slot-swizzled ps = L ^ (L>>2) (reads conflict-free),
// padded to ~90 KB so only 1 WG/CU can be resident (4 CUs, exclusive DS pipe each).
__global__ __launch_bounds__(512, 2) void rnn_mfma_kernel(const _Float16* __restrict__ Zw,   // [512][4][8][64][16]
                                                          const _Float16* __restrict__ WhT, // [512 col][512 k]
                                                          const float* __restrict__ h0,     // [512]
                                                          float* __restrict__ out) {        // [T][B][512]
    __shared__ _Float16 Ah2[2][8192];       // 32 KB: [buf][kt*512 + ps*8 + e]
    __shared__ half8_t  lds_pad[3600];      // 57.6 KB: occupancy guard (1 WG/CU)
    const int tid = threadIdx.x;
    const int w = tid >> 6, l = tid & 63;
    const int l15 = l & 15, q = l >> 4;
    const int b = blockIdx.x;               // batch rows b*16 .. b*16+15
    const int wbase = w * 64;

    ((volatile _Float16*)lds_pad)[tid] = (_Float16)0.f;   // keep pad allocated

    // ---- stage register A-fragments of W (kt 0..11): 192 regs (AGPR pool; proven allocatable)
    half8_t bw[REG_KT][4];
    #pragma unroll
    for (int kt = 0; kt < REG_KT; ++kt)
        #pragma unroll
        for (int ct = 0; ct < 4; ++ct)
            bw[kt][ct] = *(const half8_t*)(WhT + (size_t)(wbase + ct * 16 + l15) * DIM + kt * 32 + q * 8);
    #pragma unroll
    for (int kt = 0; kt < REG_KT; ++kt)
        #pragma unroll
        for (int ct = 0; ct < 4; ++ct)
            asm volatile("" : "+v"(bw[kt][ct]));

    // stream pointers for kt 12..15 (per ct); loads use imm offsets ktl*64 B
    const _Float16* pw[4];
    #pragma unroll
    for (int ct = 0; ct < 4; ++ct)
        pw[ct] = WhT + (size_t)(wbase + ct * 16 + l15) * DIM + REG_KT * 32 + q * 8;

    // ---- per-ct h-write offsets (loop-invariant): kt = w*2+(ct>>1),
    //      lane-slot Lt = ((ct&1)*2 + (q>>1))*16 + l15, elem base e0 = (q&1)*4
    int aw_off[4];
    #pragma unroll
    for (int ct = 0; ct < 4; ++ct) {
        const int kt = w * 2 + (ct >> 1);
        const int Lt = ((ct & 1) * 2 + (q >> 1)) * 16 + l15;
        const int ps = Lt ^ (Lt >> 2);
        aw_off[ct] = kt * 512 + ps * 8 + (q & 1) * 4;
    }

    // ---- h0: out[0] plane (exact f32 passthrough) + Ah2[0] init (f16)
    float* p0 = out + (size_t)(b * 16 + l15) * DIM + wbase + q * 4;
    #pragma unroll
    for (int ct = 0; ct < 4; ++ct) {
        const float4 hv = *(const float4*)(h0 + wbase + ct * 16 + q * 4);
        *(float4*)(p0 + ct * 16) = hv;
        half4_t hh;
        hh[0] = (_Float16)hv.x; hh[1] = (_Float16)hv.y;
        hh[2] = (_Float16)hv.z; hh[3] = (_Float16)hv.w;
        *(half4_t*)(&Ah2[0][0] + aw_off[ct]) = hh;
    }
    __syncthreads();

    const int psl = (l ^ (l >> 2)) * 8;                    // h-frag read slot base (elems)
    const _Float16* pz = Zw + ((size_t)(b * 8 + w) * 64 + l) * 16;
    half8_t z0 = *(const half8_t*)(pz);
    half8_t z1 = *(const half8_t*)(pz + 8);
    float* pout = out + (size_t)(BATCH + b * 16 + l15) * DIM + wbase + q * 4;   // t=1 plane

    for (int t = 0; t < T_STEPS - 1; ++t) {
        const _Float16* Ahr = Ah2[t & 1];
        _Float16*       Ahw = Ah2[(t + 1) & 1];
        // acc init = z_t (f16 -> f32)
        f32x4 acc[4];
        #pragma unroll
        for (int ct = 0; ct < 4; ++ct)
            #pragma unroll
            for (int rg = 0; rg < 4; ++rg) {
                const int i = ct * 4 + rg;
                acc[ct][rg] = (float)(i < 8 ? z0[i] : z1[i - 8]);
            }
        // prefetch z_{t+1} and the 4 streamed W k-tiles (VMEM, in flight across MFMA phase)
        half8_t zn0 = *(const half8_t*)(pz + (size_t)(t + 1) * 32768);
        half8_t zn1 = *(const half8_t*)(pz + (size_t)(t + 1) * 32768 + 8);
        half8_t sw[STR_KT][4];
        #pragma unroll
        for (int ktl = 0; ktl < STR_KT; ++ktl)
            #pragma unroll
            for (int ct = 0; ct < 4; ++ct)
                sw[ktl][ct] = *(const half8_t*)(pw[ct] + ktl * 32);

        // ---- MFMA phase: 16 k-tiles x 4 col-tiles = 64 MFMA (A=W, B=h)
        __builtin_amdgcn_s_setprio(1);
        #pragma unroll
        for (int kt = 0; kt < REG_KT; ++kt) {
            half8_t hf = *(const half8_t*)(Ahr + kt * 512 + psl);
            #pragma unroll
            for (int ct = 0; ct < 4; ++ct)
                acc[ct] = __builtin_amdgcn_mfma_f32_16x16x32_f16(bw[kt][ct], hf, acc[ct], 0, 0, 0);
        }
        #pragma unroll
        for (int ktl = 0; ktl < STR_KT; ++ktl) {
            half8_t hf = *(const half8_t*)(Ahr + (REG_KT + ktl) * 512 + psl);
            #pragma unroll
            for (int ct = 0; ct < 4; ++ct)
                acc[ct] = __builtin_amdgcn_mfma_f32_16x16x32_f16(sw[ktl][ct], hf, acc[ct], 0, 0, 0);
        }
        __builtin_amdgcn_s_setprio(0);

        // ---- epilogue: tanh, ONE b64 h-write + ONE b128 out-store per ct
        #pragma unroll
        for (int ct = 0; ct < 4; ++ct) {
            float4 hv;
            hv.x = fast_tanh(acc[ct][0]);
            hv.y = fast_tanh(acc[ct][1]);
            hv.z = fast_tanh(acc[ct][2]);
            hv.w = fast_tanh(acc[ct][3]);
            half4_t hh;
            hh[0] = (_Float16)hv.x; hh[1] = (_Float16)hv.y;
            hh[2] = (_Float16)hv.z; hh[3] = (_Float16)hv.w;
            *(half4_t*)(Ahw + aw_off[ct]) = hh;
            *(float4*)(pout + ct * 16) = hv;
        }

        z0 = zn0; z1 = zn1;
        pout += BATCH * DIM;
        // single barrier: this wave's LDS ops drained; VMEM (out-stores, prefetch) stays in flight
        asm volatile("s_waitcnt lgkmcnt(0)\n\ts_barrier" ::: "memory");
    }
}

extern "C" void kernel_launch(void* const* d_in, const int* in_sizes, int n_in,
                              void* d_out, int out_size, void* d_ws, size_t ws_size,
                              hipStream_t stream) {
    const float* X    = (const float*)d_in[0];   // [512][64][512]
    const float* W    = (const float*)d_in[1];   // [1024][512]
    const float* bias = (const float*)d_in[2];   // [512]
    const float* h0   = (const float*)d_in[3];   // [512]
    float* out = (float*)d_out;

    char* ws = (char*)d_ws;
    unsigned short* WxT = (unsigned short*)(ws);                 //    524,288 B
    _Float16*       WhT = (_Float16*)(ws + 524288);              //    524,288 B  [col][k] f16
    _Float16*       Zws = (_Float16*)(ws + 1048576);             // 33,554,432 B  frag-ordered Z
                                                                  // total 34,603,008 B

    dim3 tb(32, 8);
    tr_cvt_kernel<<<dim3(16, 16), tb, 0, stream>>>(W, WxT);                    // Wx^T bf16
    tr_cvt_f16_kernel<<<dim3(16, 16), tb, 0, stream>>>(W + 512 * 512, WhT);    // Wh^T f16
    gemm_z_kernel<<<dim3(4, 256), 256, 0, stream>>>(X, WxT, bias, Zws);
    rnn_mfma_kernel<<<4, 512, 0, stream>>>(Zws, WhT, h0, out);
}

// Round 6
// 1580.087 us; speedup vs baseline: 1.5197x; 1.5197x over previous
//
#include <hip/hip_runtime.h>
#include <hip/hip_bf16.h>
#include <hip/hip_fp16.h>

#define T_STEPS 512
#define BATCH   64
#define DIM     512            // INPUT_DIM == RNN_DIM
#define REG_KT  14             // k-tiles of Wh pinned in registers (224 regs)
#define LDS_KT  2              // k-tiles of Wh in LDS pool (64 KB, self-read slots)

typedef _Float16 half2_t __attribute__((ext_vector_type(2)));
typedef _Float16 half4_t __attribute__((ext_vector_type(4)));
typedef _Float16 half8_t __attribute__((ext_vector_type(8)));
typedef short    bf16x8 __attribute__((ext_vector_type(8)));
typedef float    f32x4  __attribute__((ext_vector_type(4)));

static __device__ __forceinline__ unsigned short f2bf(float f) {
    union { float f; unsigned u; } v; v.f = f;
    unsigned r = v.u + 0x7fffu + ((v.u >> 16) & 1u);   // RNE
    return (unsigned short)(r >> 16);
}

static __device__ __forceinline__ float fast_tanh(float x) {
    float e = __expf(2.0f * x);
    return 1.0f - 2.0f * __builtin_amdgcn_rcpf(e + 1.0f);
}

// ------------- K1: transpose 512x512 fp32 region -> bf16 (for Wx^T, gemm B-operand) -------------
__global__ __launch_bounds__(256) void tr_cvt_kernel(const float* __restrict__ src,
                                                     unsigned short* __restrict__ dst) {
    __shared__ float tile[32][33];
    const int bx = blockIdx.x * 32;
    const int by = blockIdx.y * 32;
    const int tx = threadIdx.x;       // 32
    const int ty = threadIdx.y;       // 8
    #pragma unroll
    for (int i = ty; i < 32; i += 8)
        tile[i][tx] = src[(size_t)(by + i) * DIM + (bx + tx)];
    __syncthreads();
    #pragma unroll
    for (int i = ty; i < 32; i += 8)
        dst[(size_t)(bx + i) * DIM + (by + tx)] = f2bf(tile[tx][i]);
}

// ------------- K1c: transpose Wh (rows 512..1023 of W) -> f16 WhT[col][k] -------------
__global__ __launch_bounds__(256) void tr_cvt_f16_kernel(const float* __restrict__ src,  // W + 512*512
                                                         _Float16* __restrict__ dst) {  // [512 col][512 k]
    __shared__ float tile[32][33];
    const int bx = blockIdx.x * 32;
    const int by = blockIdx.y * 32;
    const int tx = threadIdx.x;
    const int ty = threadIdx.y;
    #pragma unroll
    for (int i = ty; i < 32; i += 8)
        tile[i][tx] = src[(size_t)(by + i) * DIM + (bx + tx)];
    __syncthreads();
    #pragma unroll
    for (int i = ty; i < 32; i += 8)
        dst[(size_t)(bx + i) * DIM + (by + tx)] = (_Float16)tile[tx][i];
}

// ---------------- K2: Z = X @ Wx + bias  (bf16 MFMA), output in K3 per-thread frag order --------
// K3 thread (w, l=q*16+l15) in WG b owns Z[brow=b*16+l15][col=w*64+ct*16+q*4+rg] at i=ct*4+rg.
// Zws[t][(b*8+w)*64 + l][i]
__global__ __launch_bounds__(256) void gemm_z_kernel(const float* __restrict__ X,            // [32768][512] f32
                                                     const unsigned short* __restrict__ WxT, // [512 n][512 k] bf16
                                                     const float* __restrict__ bias,         // [512]
                                                     _Float16* __restrict__ Zo) {            // [512][4][8][64][16] f16
    const int bm   = blockIdx.y;
    const int bn   = blockIdx.x;
    const int wave = threadIdx.x >> 6;
    const int lane = threadIdx.x & 63;
    const int mBase = bm * 128 + (wave >> 1) * 64;
    const int nBase = bn * 128 + (wave & 1) * 64;
    const int l15 = lane & 15;
    const int q   = lane >> 4;
    f32x4 acc[4][4] = {};
    for (int kt = 0; kt < 512; kt += 32) {
        const int kk = kt + q * 8;
        bf16x8 a[4], b[4];
        #pragma unroll
        for (int i = 0; i < 4; ++i) {
            const float* ap = X + (size_t)(mBase + i * 16 + l15) * DIM + kk;
            float4 f0 = *(const float4*)(ap);
            float4 f1 = *(const float4*)(ap + 4);
            bf16x8 av;
            av[0] = (short)f2bf(f0.x); av[1] = (short)f2bf(f0.y);
            av[2] = (short)f2bf(f0.z); av[3] = (short)f2bf(f0.w);
            av[4] = (short)f2bf(f1.x); av[5] = (short)f2bf(f1.y);
            av[6] = (short)f2bf(f1.z); av[7] = (short)f2bf(f1.w);
            a[i] = av;
        }
        #pragma unroll
        for (int i = 0; i < 4; ++i)
            b[i] = *(const bf16x8*)(WxT + (size_t)(nBase + i * 16 + l15) * DIM + kk);
        #pragma unroll
        for (int mi = 0; mi < 4; ++mi)
            #pragma unroll
            for (int ni = 0; ni < 4; ++ni)
                acc[mi][ni] = __builtin_amdgcn_mfma_f32_16x16x32_bf16(a[mi], b[ni], acc[mi][ni], 0, 0, 0);
    }
    #pragma unroll
    for (int ni = 0; ni < 4; ++ni) {
        const int col = nBase + ni * 16 + l15;
        const float bv = bias[col];
        const int w_  = col >> 6;
        const int c64 = col & 63;
        const int ct_ = c64 >> 4;
        const int q_  = (c64 & 15) >> 2;
        const int rg_ = c64 & 3;
        #pragma unroll
        for (int mi = 0; mi < 4; ++mi) {
            #pragma unroll
            for (int rg = 0; rg < 4; ++rg) {
                const int row = mBase + mi * 16 + q * 4 + rg;
                const int t_ = row >> 6, batch = row & 63;
                const int b_ = batch >> 4, l15k = batch & 15;
                Zo[(size_t)t_ * 32768 + (size_t)((b_ * 8 + w_) * 64 + (q_ * 16 + l15k)) * 16 + ct_ * 4 + rg_] =
                    (_Float16)(acc[mi][ni][rg] + bv);
            }
        }
    }
}

// ---------------- K3: C^T MFMA recurrence, 4 WGs x 512 thr; 16 batch rows per WG ----------------
// mfma_f32_16x16x32_f16(A=W-frag, B=h-frag):
//   A: lane L holds WhT[col'=ct*16+(L&15)+wbase][k=kt*32+(L>>4)*8+e]
//   B: lane L holds h[brow=L&15][same k]
//   C: thread holds (brow=L&15, cols = (L>>4)*4+rg + ct*16 + wbase)
// => thread's 4 rg values = 4 consecutive k-elems of one h-frag slot: ONE ds_write_b64 per ct,
//    and out-stores are 4x global_store_dwordx4.
// W is FULLY CU-RESIDENT (R5 lesson: in-loop global W streaming is miss-concurrency-bound and
// costs ~5k cyc/step at 2 waves/SIMD): 14 k-tiles pinned in 224 regs (AGPR-native as MFMA A),
// 2 k-tiles in a 64 KB LDS pool (each thread stores & reloads its own fragment slot).
// h: double-buffered 2x16 KB, slot-swizzled ps = L ^ (L>>2) (reads conflict-free).
// LDS total 96 KB -> 1 WG/CU. Zero in-loop global loads except the 2 z-prefetches.
__global__ __launch_bounds__(512, 2) void rnn_mfma_kernel(const _Float16* __restrict__ Zw,   // [512][4][8][64][16]
                                                          const _Float16* __restrict__ WhT, // [512 col][512 k]
                                                          const float* __restrict__ h0,     // [512]
                                                          float* __restrict__ out) {        // [T][B][512]
    __shared__ _Float16 Ah2[2][8192];       // 32 KB: [buf][kt*512 + ps*8 + e]
    __shared__ _Float16 WlA[32768];         // 64 KB: (w*8 + ct*2 + ktl)*512 + l*8
    const int tid = threadIdx.x;
    const int w = tid >> 6, l = tid & 63;
    const int l15 = l & 15, q = l >> 4;
    const int b = blockIdx.x;               // batch rows b*16 .. b*16+15
    const int wbase = w * 64;

    // ---- stage register A-fragments of W (kt 0..13): 224 regs
    half8_t bw[REG_KT][4];
    #pragma unroll
    for (int kt = 0; kt < REG_KT; ++kt)
        #pragma unroll
        for (int ct = 0; ct < 4; ++ct)
            bw[kt][ct] = *(const half8_t*)(WhT + (size_t)(wbase + ct * 16 + l15) * DIM + kt * 32 + q * 8);
    #pragma unroll
    for (int kt = 0; kt < REG_KT; ++kt)
        #pragma unroll
        for (int ct = 0; ct < 4; ++ct)
            asm volatile("" : "+v"(bw[kt][ct]));

    // ---- stage LDS A-fragments of W (kt 14..15): per-thread self-read slots (proven R3 pattern)
    #pragma unroll
    for (int ktl = 0; ktl < LDS_KT; ++ktl)
        #pragma unroll
        for (int ct = 0; ct < 4; ++ct) {
            half8_t v = *(const half8_t*)(WhT + (size_t)(wbase + ct * 16 + l15) * DIM + (REG_KT + ktl) * 32 + q * 8);
            *(half8_t*)(WlA + ((w * 8 + ct * 2 + ktl) * 512 + l * 8)) = v;
        }

    // ---- per-ct h-write offsets (loop-invariant): kt = w*2+(ct>>1),
    //      lane-slot Lt = ((ct&1)*2 + (q>>1))*16 + l15, elem base e0 = (q&1)*4
    int aw_off[4];
    #pragma unroll
    for (int ct = 0; ct < 4; ++ct) {
        const int kt = w * 2 + (ct >> 1);
        const int Lt = ((ct & 1) * 2 + (q >> 1)) * 16 + l15;
        const int ps = Lt ^ (Lt >> 2);
        aw_off[ct] = kt * 512 + ps * 8 + (q & 1) * 4;
    }

    // ---- h0: out[0] plane (exact f32 passthrough) + Ah2[0] init (f16)
    float* p0 = out + (size_t)(b * 16 + l15) * DIM + wbase + q * 4;
    #pragma unroll
    for (int ct = 0; ct < 4; ++ct) {
        const float4 hv = *(const float4*)(h0 + wbase + ct * 16 + q * 4);
        *(float4*)(p0 + ct * 16) = hv;
        half4_t hh;
        hh[0] = (_Float16)hv.x; hh[1] = (_Float16)hv.y;
        hh[2] = (_Float16)hv.z; hh[3] = (_Float16)hv.w;
        *(half4_t*)(&Ah2[0][0] + aw_off[ct]) = hh;
    }
    __syncthreads();

    const int psl = (l ^ (l >> 2)) * 8;                    // h-frag read slot base (elems)
    const _Float16* pz = Zw + ((size_t)(b * 8 + w) * 64 + l) * 16;
    half8_t z0 = *(const half8_t*)(pz);
    half8_t z1 = *(const half8_t*)(pz + 8);
    float* pout = out + (size_t)(BATCH + b * 16 + l15) * DIM + wbase + q * 4;   // t=1 plane

    for (int t = 0; t < T_STEPS - 1; ++t) {
        const _Float16* Ahr = Ah2[t & 1];
        _Float16*       Ahw = Ah2[(t + 1) & 1];
        // acc init = z_t (f16 -> f32)
        f32x4 acc[4];
        #pragma unroll
        for (int ct = 0; ct < 4; ++ct)
            #pragma unroll
            for (int rg = 0; rg < 4; ++rg) {
                const int i = ct * 4 + rg;
                acc[ct][rg] = (float)(i < 8 ? z0[i] : z1[i - 8]);
            }
        // prefetch z_{t+1} (in flight across the MFMA phase; consumed after next barrier)
        half8_t zn0 = *(const half8_t*)(pz + (size_t)(t + 1) * 32768);
        half8_t zn1 = *(const half8_t*)(pz + (size_t)(t + 1) * 32768 + 8);

        // ---- MFMA phase: 16 k-tiles x 4 col-tiles = 64 MFMA (A=W, B=h)
        __builtin_amdgcn_s_setprio(1);
        #pragma unroll
        for (int kt = 0; kt < REG_KT; ++kt) {
            half8_t hf = *(const half8_t*)(Ahr + kt * 512 + psl);
            #pragma unroll
            for (int ct = 0; ct < 4; ++ct)
                acc[ct] = __builtin_amdgcn_mfma_f32_16x16x32_f16(bw[kt][ct], hf, acc[ct], 0, 0, 0);
        }
        #pragma unroll
        for (int ktl = 0; ktl < LDS_KT; ++ktl) {
            half8_t hf = *(const half8_t*)(Ahr + (REG_KT + ktl) * 512 + psl);
            #pragma unroll
            for (int ct = 0; ct < 4; ++ct) {
                half8_t wf = *(const half8_t*)(WlA + ((w * 8 + ct * 2 + ktl) * 512 + l * 8));
                acc[ct] = __builtin_amdgcn_mfma_f32_16x16x32_f16(wf, hf, acc[ct], 0, 0, 0);
            }
        }
        __builtin_amdgcn_s_setprio(0);

        // ---- epilogue: tanh, ONE b64 h-write + ONE b128 out-store per ct
        #pragma unroll
        for (int ct = 0; ct < 4; ++ct) {
            float4 hv;
            hv.x = fast_tanh(acc[ct][0]);
            hv.y = fast_tanh(acc[ct][1]);
            hv.z = fast_tanh(acc[ct][2]);
            hv.w = fast_tanh(acc[ct][3]);
            half4_t hh;
            hh[0] = (_Float16)hv.x; hh[1] = (_Float16)hv.y;
            hh[2] = (_Float16)hv.z; hh[3] = (_Float16)hv.w;
            *(half4_t*)(Ahw + aw_off[ct]) = hh;
            *(float4*)(pout + ct * 16) = hv;
        }

        z0 = zn0; z1 = zn1;
        pout += BATCH * DIM;
        // single barrier: this wave's LDS ops drained; VMEM (out-stores, z-prefetch) stays in flight
        asm volatile("s_waitcnt lgkmcnt(0)\n\ts_barrier" ::: "memory");
    }
}

extern "C" void kernel_launch(void* const* d_in, const int* in_sizes, int n_in,
                              void* d_out, int out_size, void* d_ws, size_t ws_size,
                              hipStream_t stream) {
    const float* X    = (const float*)d_in[0];   // [512][64][512]
    const float* W    = (const float*)d_in[1];   // [1024][512]
    const float* bias = (const float*)d_in[2];   // [512]
    const float* h0   = (const float*)d_in[3];   // [512]
    float* out = (float*)d_out;

    char* ws = (char*)d_ws;
    unsigned short* WxT = (unsigned short*)(ws);                 //    524,288 B
    _Float16*       WhT = (_Float16*)(ws + 524288);              //    524,288 B  [col][k] f16
    _Float16*       Zws = (_Float16*)(ws + 1048576);             // 33,554,432 B  frag-ordered Z
                                                                  // total 34,603,008 B

    dim3 tb(32, 8);
    tr_cvt_kernel<<<dim3(16, 16), tb, 0, stream>>>(W, WxT);                    // Wx^T bf16
    tr_cvt_f16_kernel<<<dim3(16, 16), tb, 0, stream>>>(W + 512 * 512, WhT);    // Wh^T f16
    gemm_z_kernel<<<dim3(4, 256), 256, 0, stream>>>(X, WxT, bias, Zws);
    rnn_mfma_kernel<<<4, 512, 0, stream>>>(Zws, WhT, h0, out);
}

// Round 7
// 1364.395 us; speedup vs baseline: 1.7599x; 1.1581x over previous
//
#include <hip/hip_runtime.h>
#include <hip/hip_bf16.h>
#include <hip/hip_fp16.h>

#define T_STEPS 512
#define BATCH   64
#define DIM     512            // INPUT_DIM == RNN_DIM

typedef _Float16 half2_t __attribute__((ext_vector_type(2)));
typedef _Float16 half8_t __attribute__((ext_vector_type(8)));
typedef short    bf16x8 __attribute__((ext_vector_type(8)));
typedef float    f32x4  __attribute__((ext_vector_type(4)));

static __device__ __forceinline__ unsigned short f2bf(float f) {
    union { float f; unsigned u; } v; v.f = f;
    unsigned r = v.u + 0x7fffu + ((v.u >> 16) & 1u);   // RNE
    return (unsigned short)(r >> 16);
}

static __device__ __forceinline__ float fast_tanh(float x) {
    float e = __expf(2.0f * x);
    return 1.0f - 2.0f * __builtin_amdgcn_rcpf(e + 1.0f);
}

// ------------- K1: transpose 512x512 fp32 region -> bf16 (for Wx^T, gemm B-operand) -------------
__global__ __launch_bounds__(256) void tr_cvt_kernel(const float* __restrict__ src,
                                                     unsigned short* __restrict__ dst) {
    __shared__ float tile[32][33];
    const int bx = blockIdx.x * 32;
    const int by = blockIdx.y * 32;
    const int tx = threadIdx.x;       // 32
    const int ty = threadIdx.y;       // 8
    #pragma unroll
    for (int i = ty; i < 32; i += 8)
        tile[i][tx] = src[(size_t)(by + i) * DIM + (bx + tx)];
    __syncthreads();
    #pragma unroll
    for (int i = ty; i < 32; i += 8)
        dst[(size_t)(bx + i) * DIM + (by + tx)] = f2bf(tile[tx][i]);
}

// ------------- K1c: transpose Wh (rows 512..1023 of W) -> f16 WhT[col][k] -------------
__global__ __launch_bounds__(256) void tr_cvt_f16_kernel(const float* __restrict__ src,  // W + 512*512
                                                         _Float16* __restrict__ dst) {  // [512 col][512 k]
    __shared__ float tile[32][33];
    const int bx = blockIdx.x * 32;
    const int by = blockIdx.y * 32;
    const int tx = threadIdx.x;
    const int ty = threadIdx.y;
    #pragma unroll
    for (int i = ty; i < 32; i += 8)
        tile[i][tx] = src[(size_t)(by + i) * DIM + (bx + tx)];
    __syncthreads();
    #pragma unroll
    for (int i = ty; i < 32; i += 8)
        dst[(size_t)(bx + i) * DIM + (by + tx)] = (_Float16)tile[tx][i];
}

// ---------------- K2: Z = X @ Wx + bias  (bf16 MFMA), output in K3 per-thread frag order --------
// Zws[t][b][w][l][i]: i = ct*4+rg for value at (batch row = b*16 + (l>>4)*4+rg,
//                                              col = w*64 + ct*16 + (l&15))
__global__ __launch_bounds__(256) void gemm_z_kernel(const float* __restrict__ X,            // [32768][512] f32
                                                     const unsigned short* __restrict__ WxT, // [512 n][512 k] bf16
                                                     const float* __restrict__ bias,         // [512]
                                                     _Float16* __restrict__ Zo) {            // [512][4][8][64][16] f16
    const int bm   = blockIdx.y;
    const int bn   = blockIdx.x;
    const int wave = threadIdx.x >> 6;
    const int lane = threadIdx.x & 63;
    const int mBase = bm * 128 + (wave >> 1) * 64;
    const int nBase = bn * 128 + (wave & 1) * 64;
    const int l15 = lane & 15;
    const int q   = lane >> 4;
    f32x4 acc[4][4] = {};
    for (int kt = 0; kt < 512; kt += 32) {
        const int kk = kt + q * 8;
        bf16x8 a[4], b[4];
        #pragma unroll
        for (int i = 0; i < 4; ++i) {
            const float* ap = X + (size_t)(mBase + i * 16 + l15) * DIM + kk;
            float4 f0 = *(const float4*)(ap);
            float4 f1 = *(const float4*)(ap + 4);
            bf16x8 av;
            av[0] = (short)f2bf(f0.x); av[1] = (short)f2bf(f0.y);
            av[2] = (short)f2bf(f0.z); av[3] = (short)f2bf(f0.w);
            av[4] = (short)f2bf(f1.x); av[5] = (short)f2bf(f1.y);
            av[6] = (short)f2bf(f1.z); av[7] = (short)f2bf(f1.w);
            a[i] = av;
        }
        #pragma unroll
        for (int i = 0; i < 4; ++i)
            b[i] = *(const bf16x8*)(WxT + (size_t)(nBase + i * 16 + l15) * DIM + kk);
        #pragma unroll
        for (int mi = 0; mi < 4; ++mi)
            #pragma unroll
            for (int ni = 0; ni < 4; ++ni)
                acc[mi][ni] = __builtin_amdgcn_mfma_f32_16x16x32_bf16(a[mi], b[ni], acc[mi][ni], 0, 0, 0);
    }
    #pragma unroll
    for (int ni = 0; ni < 4; ++ni) {
        const int col = nBase + ni * 16 + l15;
        const float bv = bias[col];
        const int w_ = col >> 6, ct_ = (col >> 4) & 3, l15_ = col & 15;
        #pragma unroll
        for (int mi = 0; mi < 4; ++mi) {
            #pragma unroll
            for (int rg = 0; rg < 4; ++rg) {
                const int row = mBase + mi * 16 + q * 4 + rg;
                const int t_ = row >> 6, brow = row & 63;
                const int b_ = brow >> 4, r4 = brow & 15;
                const int l_ = (r4 >> 2) * 16 + l15_;
                const int i_ = ct_ * 4 + (r4 & 3);
                Zo[(size_t)t_ * 32768 + (size_t)((b_ * 8 + w_) * 64 + l_) * 16 + i_] =
                    (_Float16)(acc[mi][ni][rg] + bv);
            }
        }
    }
}

// ---------------- K3: MFMA recurrence, 4 WGs x 512 thr; 16 batch rows per WG ----------------
// Wave w owns cols [w*64, w*64+64). mfma_f32_16x16x32_f16:
//   A-frag (h):  lane L holds h[row=L&15][k = kt*32 + (L>>4)*8 + e]
//   B-frag (W):  lane holds WhT[col][same k]  -> C[row=(L>>4)*4+rg][col=L&15]
// W: kt 0..11 resident in 192 regs, kt 12..15 in LDS (128 KB).
// h: double-buffered 2x16 KB, slot-swizzled ps = L ^ (L>>2) (reads conflict-free).
// ROUND-7 A/B vs R3 (1131 us): exactly two deltas —
//   (1) NO s_setprio: with 2 waves/SIMD in barrier lockstep, prio-1 MFMA waves starved the
//       prio-0 epilogue/read waves (convoy); R2 (no setprio) was the fastest MFMA variant.
//   (2) TWO-PHASE pacing restored (R2 structure): plain s_barrier between MFMA phase and
//       epilogue (correctness-optional with dbuf; aligns all waves' DS read bursts vs write
//       bursts instead of mixing them in one queue window), plus the end-of-step
//       lgkmcnt(0)+barrier that publishes h(t+1).
__global__ __launch_bounds__(512, 2) void rnn_mfma_kernel(const _Float16* __restrict__ Zw,   // [512][4][8][64][16]
                                                          const _Float16* __restrict__ WhT, // [512 col][512 k]
                                                          const float* __restrict__ h0,     // [512]
                                                          float* __restrict__ out) {        // [T][B][512]
    __shared__ _Float16 WlA[65536];    // 128 KB: (w*16 + ct*4 + ktl)*512 + l*8
    __shared__ _Float16 Ah2[2][8192];  //  32 KB: [buf][kt*512 + ps*8 + e]
    const int tid = threadIdx.x;
    const int w = tid >> 6, l = tid & 63;
    const int l15 = l & 15, q = l >> 4;
    const int hi = l15 >> 3, l7 = l15 & 7;
    const int b = blockIdx.x;               // batch rows b*16 .. b*16+15
    const int wbase = w * 64;

    // ---- stage register B-fragments (kt 0..11): 192 regs (R2/R3-proven footprint)
    half8_t bw[12][4];
    #pragma unroll
    for (int kt = 0; kt < 12; ++kt)
        #pragma unroll
        for (int ct = 0; ct < 4; ++ct)
            bw[kt][ct] = *(const half8_t*)(WhT + (size_t)(wbase + ct * 16 + l15) * DIM + kt * 32 + q * 8);
    #pragma unroll
    for (int kt = 0; kt < 12; ++kt)
        #pragma unroll
        for (int ct = 0; ct < 4; ++ct)
            asm volatile("" : "+v"(bw[kt][ct]));
    // ---- stage LDS B-fragments (kt 12..15), frag-linear: read & write conflict-free
    #pragma unroll
    for (int ktl = 0; ktl < 4; ++ktl)
        #pragma unroll
        for (int ct = 0; ct < 4; ++ct) {
            half8_t v = *(const half8_t*)(WhT + (size_t)(wbase + ct * 16 + l15) * DIM + (12 + ktl) * 32 + q * 8);
            *(half8_t*)(WlA + (size_t)((w * 16 + ct * 4 + ktl) * 512 + l * 8)) = v;
        }

    // ---- h0: out[0] plane (exact f32 passthrough) + Ah2[0] init (f16, swizzled)
    float* p0 = out + (size_t)(b * 16 + q * 4) * DIM + wbase + l15;
    #pragma unroll
    for (int ct = 0; ct < 4; ++ct) {
        const float hv = h0[wbase + ct * 16 + l15];
        const int ktc = w * 2 + (ct >> 1);
        const int Lb  = ((ct & 1) * 2 + hi) * 16 + q * 4;
        #pragma unroll
        for (int rg = 0; rg < 4; ++rg) {
            p0[rg * DIM + ct * 16] = hv;
            const int L = Lb + rg;
            const int ps = L ^ (L >> 2);
            Ah2[0][ktc * 512 + ps * 8 + l7] = (_Float16)hv;
        }
    }
    __syncthreads();

    const int psl = (l ^ (l >> 2)) * 8;                    // read slot base (elems)
    const _Float16* pz = Zw + ((size_t)(b * 8 + w) * 64 + l) * 16;
    half8_t z0 = *(const half8_t*)(pz);
    half8_t z1 = *(const half8_t*)(pz + 8);
    float* pout = out + (size_t)(BATCH + b * 16 + q * 4) * DIM + wbase + l15;   // t=1 plane

    for (int t = 0; t < T_STEPS - 1; ++t) {
        const _Float16* Ahr = Ah2[t & 1];
        _Float16*       Ahw = Ah2[(t + 1) & 1];
        // acc init = z_t (f16 -> f32)
        f32x4 acc[4];
        #pragma unroll
        for (int ct = 0; ct < 4; ++ct)
            #pragma unroll
            for (int rg = 0; rg < 4; ++rg) {
                const int i = ct * 4 + rg;
                acc[ct][rg] = (float)(i < 8 ? z0[i] : z1[i - 8]);
            }
        // prefetch z_{t+1} (stays in flight across the MFMA phase)
        half8_t zn0 = *(const half8_t*)(pz + (size_t)(t + 1) * 32768);
        half8_t zn1 = *(const half8_t*)(pz + (size_t)(t + 1) * 32768 + 8);

        // ---- MFMA phase: 16 k-tiles x 4 col-tiles = 64 MFMA (no setprio)
        #pragma unroll
        for (int kt = 0; kt < 12; ++kt) {
            half8_t af = *(const half8_t*)(Ahr + kt * 512 + psl);
            #pragma unroll
            for (int ct = 0; ct < 4; ++ct)
                acc[ct] = __builtin_amdgcn_mfma_f32_16x16x32_f16(af, bw[kt][ct], acc[ct], 0, 0, 0);
        }
        #pragma unroll
        for (int ktl = 0; ktl < 4; ++ktl) {
            half8_t af = *(const half8_t*)(Ahr + (12 + ktl) * 512 + psl);
            #pragma unroll
            for (int ct = 0; ct < 4; ++ct) {
                half8_t wf = *(const half8_t*)(WlA + (size_t)((w * 16 + ct * 4 + ktl) * 512 + l * 8));
                acc[ct] = __builtin_amdgcn_mfma_f32_16x16x32_f16(af, wf, acc[ct], 0, 0, 0);
            }
        }

        // mid barrier: phase alignment (R2 pacing) — dbuf makes it correctness-optional,
        // so no lgkm drain needed (each wave's own reads were consumed by its MFMAs).
        asm volatile("s_barrier" ::: "memory");

        // ---- epilogue: tanh, swizzled f16 scatter to OTHER Ah buffer, f32 out stores
        float hv[4][4];
        #pragma unroll
        for (int ct = 0; ct < 4; ++ct)
            #pragma unroll
            for (int rg = 0; rg < 4; ++rg)
                hv[ct][rg] = fast_tanh(acc[ct][rg]);
        #pragma unroll
        for (int ct = 0; ct < 4; ++ct) {
            const int ktc = w * 2 + (ct >> 1);
            const int Lb  = ((ct & 1) * 2 + hi) * 16 + q * 4;
            #pragma unroll
            for (int rg = 0; rg < 4; ++rg) {
                const int L = Lb + rg;
                const int ps = L ^ (L >> 2);
                Ahw[ktc * 512 + ps * 8 + l7] = (_Float16)hv[ct][rg];
            }
        }
        #pragma unroll
        for (int ct = 0; ct < 4; ++ct)
            #pragma unroll
            for (int rg = 0; rg < 4; ++rg)
                pout[rg * DIM + ct * 16] = hv[ct][rg];

        z0 = zn0; z1 = zn1;
        pout += BATCH * DIM;
        // end barrier: h(t+1) writes drained (LDS only); out-stores / z-prefetch stay in flight
        asm volatile("s_waitcnt lgkmcnt(0)\n\ts_barrier" ::: "memory");
    }
}

extern "C" void kernel_launch(void* const* d_in, const int* in_sizes, int n_in,
                              void* d_out, int out_size, void* d_ws, size_t ws_size,
                              hipStream_t stream) {
    const float* X    = (const float*)d_in[0];   // [512][64][512]
    const float* W    = (const float*)d_in[1];   // [1024][512]
    const float* bias = (const float*)d_in[2];   // [512]
    const float* h0   = (const float*)d_in[3];   // [512]
    float* out = (float*)d_out;

    char* ws = (char*)d_ws;
    unsigned short* WxT = (unsigned short*)(ws);                 //    524,288 B
    _Float16*       WhT = (_Float16*)(ws + 524288);              //    524,288 B  [col][k] f16
    _Float16*       Zws = (_Float16*)(ws + 1048576);             // 33,554,432 B  frag-ordered Z
                                                                  // total 34,603,008 B

    dim3 tb(32, 8);
    tr_cvt_kernel<<<dim3(16, 16), tb, 0, stream>>>(W, WxT);                    // Wx^T bf16
    tr_cvt_f16_kernel<<<dim3(16, 16), tb, 0, stream>>>(W + 512 * 512, WhT);    // Wh^T f16
    gemm_z_kernel<<<dim3(4, 256), 256, 0, stream>>>(X, WxT, bias, Zws);
    rnn_mfma_kernel<<<4, 512, 0, stream>>>(Zws, WhT, h0, out);
}